// Round 1
// baseline (1927.254 us; speedup 1.0000x reference)
//
#include <hip/hip_runtime.h>
#include <hip/hip_bf16.h>
#include <cstring>

// ---- problem constants ----
#define NB 8
#define NT 64
#define NNODE 24
#define ND 6
#define NH 128
#define NR 64
#define NNE 4
#define NEDGE 552                  // NNODE*(NNODE-1)
#define NSEQ (NB*NEDGE)            // 4416
#define ROWS1 (NB*NNODE*NT)        // 12288
#define ROWS2 (NB*NEDGE*NT)        // 282624
#define PRIOR_SZ (NB*NT*NEDGE*NNE) // 1130496

typedef __hip_bfloat16 bf16;
typedef unsigned short u16;
typedef unsigned int u32;
typedef _Float16 f16;
typedef __attribute__((ext_vector_type(2))) _Float16 f16x2;
typedef __attribute__((ext_vector_type(8))) _Float16 f16x8;
typedef __attribute__((ext_vector_type(4))) float f32x4;

__device__ __forceinline__ float eluf(float x){ return x > 0.f ? x : expm1f(x); }
__device__ __forceinline__ float b2f(bf16 v){ return __bfloat162float(v); }
__device__ __forceinline__ u16 f2h(float x){ f16 h = (f16)x; u16 v; __builtin_memcpy(&v, &h, 2); return v; }
__device__ __forceinline__ float h2f(u16 v){ f16 h; __builtin_memcpy(&h, &v, 2); return (float)h; }
__device__ __forceinline__ u32 packf2(float a, float b){ return (u32)f2h(a) | ((u32)f2h(b) << 16); }

#if defined(__has_builtin)
#if __has_builtin(__builtin_amdgcn_fdot2)
#define HAS_DOT2 1
#endif
#endif

#ifdef HAS_DOT2
__device__ __forceinline__ float dot2(u32 a, u32 b, float c){
  f16x2 av, bv;
  __builtin_memcpy(&av, &a, 4); __builtin_memcpy(&bv, &b, 4);
  return __builtin_amdgcn_fdot2(av, bv, c, false);
}
#else
__device__ __forceinline__ float dot2(u32 a, u32 b, float c){
  return c + h2f((u16)a)*h2f((u16)b) + h2f((u16)(a>>16))*h2f((u16)(b>>16));
}
#endif

// ---------------- diagnostics / setup ----------------
__global__ void k_fill(float* out, int n, float pat){
  const int i = blockIdx.x*256 + threadIdx.x;
  if(i < n) out[i] = pat;
}
__global__ void k_zero(float* aux){
  for(int i = threadIdx.x; i < 1024; i += 256) aux[i] = 0.f;
}

// pack MLP2/MLP4 weights as k-pair f16x2: wP[k2*NH + j] = (w[2k2][j], w[2k2+1][j])
__global__ void k_prep_mlp(const float* w2a, const float* w2b,
                           const float* w4a, const float* w4b,
                           u32* w2aP, u32* w2bP, u32* w4aP, u32* w4bP)
{
  const int i = blockIdx.x*256 + threadIdx.x;
  const int k2 = i >> 7, j = i & 127;
  if(i < 128*128)
    w2aP[k2*NH + j] = packf2(w2a[(2*k2)*NH + j], w2a[(2*k2+1)*NH + j]);
  if(i < 64*128){
    w2bP[k2*NH + j] = packf2(w2b[(2*k2)*NH + j], w2b[(2*k2+1)*NH + j]);
    w4bP[k2*NH + j] = packf2(w4b[(2*k2)*NH + j], w4b[(2*k2+1)*NH + j]);
  }
  if(i < 192*128)
    w4aP[k2*NH + j] = packf2(w4a[(2*k2)*NH + j], w4a[(2*k2+1)*NH + j]);
}

// GRU weight prep (runs after MLP4; X region dead):
//  - wih: straight f16 row-major [192][128]  (MFMA B-operand, B[k][n]=wih[n][k])
//  - whh: pair-transposed f16x2 for the dot2 recurrence (unchanged)
__global__ void k_prep(const float* wihF, const float* whhF,
                       const float* wihR, const float* whhR,
                       u16* wpF, u32* whhPF, u16* wpR, u32* whhPR)
{
  const int i = blockIdx.x*256 + threadIdx.x;
  if(i < 192*128){
    wpF[i] = f2h(wihF[i]);
    wpR[i] = f2h(wihR[i]);
  }
  if(i < 192*32){
    const int r = i >> 5, k2 = i & 31;
    whhPF[k2*192 + r] = packf2(whhF[r*NR + 2*k2], whhF[r*NR + 2*k2 + 1]);
    whhPR[k2*192 + r] = packf2(whhR[r*NR + 2*k2], whhR[r*NR + 2*k2 + 1]);
  }
}

// ---------------- MLP1: (B,N,T,D)->H->H, pre-BN out + channel sums -------------
__global__ __launch_bounds__(128) void k_mlp1(
    const float* inp, const float* w1, const float* b1,
    const float* w2, const float* b2,
    float* X1, float* sum, float* sq)
{
  const int j = threadIdx.x;
  __shared__ float xin[ND];
  __shared__ float h1[NH];
  const float b1j = b1[j], b2j = b2[j];
  float wcol[ND];
  for(int d = 0; d < ND; d++) wcol[d] = w1[d*NH + j];
  float accS = 0.f, accQ = 0.f;
  const int row0 = blockIdx.x*16;
  for(int r = 0; r < 16; r++){
    const int row = row0 + r;
    const int b = row/(NNODE*NT); const int rem = row - b*(NNODE*NT);
    const int n = rem/NT; const int t = rem - n*NT;
    if(j < ND) xin[j] = inp[((b*NT + t)*NNODE + n)*ND + j];
    __syncthreads();
    float a = b1j;
    for(int d = 0; d < ND; d++) a += xin[d]*wcol[d];
    h1[j] = eluf(a);
    __syncthreads();
    float a2 = b2j;
    for(int k = 0; k < NH; k++) a2 += h1[k]*w2[k*NH + j];
    const float h2 = eluf(a2);
    X1[row*NH + j] = h2; accS += h2; accQ += h2*h2;
    __syncthreads();
  }
  atomicAdd(&sum[j], accS); atomicAdd(&sq[j], accQ);
}

// ---------------- BN params ----------------
__global__ void k_bn(const float* sum, const float* sq,
                     const float* g, const float* be,
                     float inv_cnt, float* sc, float* sh)
{
  const int j = threadIdx.x;
  const float m = sum[j]*inv_cnt;
  const float v = fmaxf(sq[j]*inv_cnt - m*m, 0.f);
  const float s = g[j]*rsqrtf(v + 1e-5f);
  sc[j] = s; sh[j] = be[j] - m*s;
}

// ---------------- edge MLPs (MLP2: KIN=256, MLP4: KIN=384), CH=16, f16 dot2 ----
template<int KIN>
__global__ __launch_bounds__(128) void k_mlp_edge(
  const float* Xn, const float* scN, const float* shN,
  const bf16* Ein, const float* scE, const float* shE,
  const u32* w1P, const float* b1, const u32* w2P, const float* b2,
  bf16* Eo, float* sum, float* sq)
{
  const int j = threadIdx.x;
  constexpr int CH = 16;
  __shared__ __align__(16) u16 xin16[CH][KIN];
  __shared__ __align__(16) u16 h1s16[CH][NH];
  const int g0 = blockIdx.x*CH;
  const int b = g0/(NEDGE*NT); const int rem = g0 - b*(NEDGE*NT);
  const int e = rem/NT; const int t0 = rem - e*NT;
  const int snd = e/23, r0 = e - snd*23;
  const int rcv = r0 + (r0 >= snd ? 1 : 0);
  const float sN = scN[j], tN = shN[j];
  float sE = 0.f, tE = 0.f;
  if constexpr(KIN == 3*NH){ sE = scE[j]; tE = shE[j]; }
  const int baseS = ((b*NNODE + snd)*NT + t0)*NH;
  const int baseR = ((b*NNODE + rcv)*NT + t0)*NH;
  for(int r = 0; r < CH; r++){
    xin16[r][j]      = f2h(Xn[baseS + r*NH + j]*sN + tN);
    xin16[r][NH + j] = f2h(Xn[baseR + r*NH + j]*sN + tN);
    if constexpr(KIN == 3*NH)
      xin16[r][2*NH + j] = f2h(b2f(Ein[(size_t)(g0 + r)*NH + j])*sE + tE);
  }
  __syncthreads();
  float acc[CH];
  const float b1j = b1[j];
  #pragma unroll
  for(int r = 0; r < CH; r++) acc[r] = b1j;
  for(int kb = 0; kb < KIN/8; kb++){
    u32 w[4];
    #pragma unroll
    for(int q = 0; q < 4; q++) w[q] = w1P[(size_t)(4*kb + q)*NH + j];
    #pragma unroll
    for(int r = 0; r < CH; r++){
      const uint4 xq = *(const uint4*)&xin16[r][8*kb];
      acc[r] = dot2(xq.x, w[0], acc[r]);
      acc[r] = dot2(xq.y, w[1], acc[r]);
      acc[r] = dot2(xq.z, w[2], acc[r]);
      acc[r] = dot2(xq.w, w[3], acc[r]);
    }
  }
  #pragma unroll
  for(int r = 0; r < CH; r++) h1s16[r][j] = f2h(eluf(acc[r]));
  __syncthreads();
  const float b2j = b2[j];
  #pragma unroll
  for(int r = 0; r < CH; r++) acc[r] = b2j;
  for(int kb = 0; kb < NH/8; kb++){
    u32 w[4];
    #pragma unroll
    for(int q = 0; q < 4; q++) w[q] = w2P[(size_t)(4*kb + q)*NH + j];
    #pragma unroll
    for(int r = 0; r < CH; r++){
      const uint4 hq = *(const uint4*)&h1s16[r][8*kb];
      acc[r] = dot2(hq.x, w[0], acc[r]);
      acc[r] = dot2(hq.y, w[1], acc[r]);
      acc[r] = dot2(hq.z, w[2], acc[r]);
      acc[r] = dot2(hq.w, w[3], acc[r]);
    }
  }
  float accS = 0.f, accQ = 0.f;
  #pragma unroll
  for(int r = 0; r < CH; r++){
    const float h2 = eluf(acc[r]);
    Eo[(size_t)(g0 + r)*NH + j] = __float2bfloat16(h2);
    accS += h2; accQ += h2*h2;
  }
  atomicAdd(&sum[j], accS); atomicAdd(&sq[j], accQ);
}

// ---------------- agg (mean over incoming edges) + MLP3 ----------------
__global__ __launch_bounds__(128) void k_mlp3(
    const bf16* Ein, const float* scE, const float* shE,
    const float* w1, const float* b1, const float* w2, const float* b2,
    float* X3, float* sum, float* sq)
{
  const int j = threadIdx.x;
  __shared__ float xin[NH];
  __shared__ float h1[NH];
  const float sE = scE[j], tE = shE[j];
  float accS = 0.f, accQ = 0.f;
  const int row0 = blockIdx.x*16;
  for(int r = 0; r < 16; r++){
    const int row = row0 + r;
    const int b = row/(NNODE*NT); const int rem = row - b*(NNODE*NT);
    const int n = rem/NT; const int t = rem - n*NT;
    float s = 0.f;
    for(int i = 0; i < NNODE; i++){
      if(i == n) continue;
      const int e = i*23 + (n < i ? n : n - 1);
      s += b2f(Ein[((size_t)(b*NEDGE + e)*NT + t)*NH + j]);
    }
    xin[j] = sE*s*(1.f/23.f) + tE;
    __syncthreads();
    float a = b1[j];
    for(int k = 0; k < NH; k++) a += xin[k]*w1[k*NH + j];
    h1[j] = eluf(a);
    __syncthreads();
    float a2 = b2[j];
    for(int k = 0; k < NH; k++) a2 += h1[k]*w2[k*NH + j];
    const float h2 = eluf(a2);
    X3[row*NH + j] = h2; accS += h2; accQ += h2*h2;
    __syncthreads();
  }
  atomicAdd(&sum[j], accS); atomicAdd(&sq[j], accQ);
}

// ---------------- GRU: 2 independent (seq,dir) units per 128-thread block -----
// Wave-private LDS => NO barriers. Input projection x@wih^T done per-16-step
// chunk with v_mfma_f32_16x16x32_f16 (A frag: lane l = A[l&15][(l>>4)*8+j],
// B frag: B[(l>>4)*8+j][l&15] from row-major wih f16, D: D[(l>>4)*4+r][l&15],
// per m97/m89-verified gfx950 layouts). Recurrence h@whh^T stays on dot2.
// Output projections computed per chunk -> hist LDS shrinks 16.9KB -> 4.2KB,
// raising the LDS occupancy cap from 4 to 6 blocks/CU.
__global__ __launch_bounds__(128, 3) void k_gru(
  const bf16* E4, const float* sc4, const float* sh4,
  const u16* wpF, const u32* whhPF, const float* bihF, const float* bhhF,
  const u16* wpR, const u32* whhPR, const float* bihR, const float* bhhR,
  const float* pw, const float* pb, const float* ew,
  bf16* encpF, bf16* encpR, float* outP, float* hT)
{
  __shared__ __align__(16) u16 xst16[2][16][NH];   // 8192 B, 16B-group XOR swizzled
  __shared__ __align__(16) u16 xwb16[2][16][192];  // 12288 B
  __shared__ __align__(16) u16 histc[2][16][66];   // 4224 B (chunk-local history)
  __shared__ __align__(16) u16 hs16[2][NR];        // 256 B
  const int tid = threadIdx.x;
  const int u = tid >> 6, c = tid & 63;
  const int gid = blockIdx.x*2 + u;
  const int dir = (gid >= NSEQ) ? 1 : 0;
  const int s = dir ? (gid - NSEQ) : gid;
  const int sb = s / NEDGE, se = s - sb*NEDGE;
  const u16* wp   = dir ? wpR : wpF;
  const u32* whhP = dir ? whhPR : whhPF;
  const float* bih = dir ? bihR : bihF;
  const float* bhh = dir ? bhhR : bhhF;
  const float bxr = bih[c], bxz = bih[64+c], bxn = bih[128+c];
  const float bhr = bhh[c], bhz = bhh[64+c], bhn = bhh[128+c];
  const float sc_a = sc4[c], sc_b = sc4[c+64];
  const float sh_a = sh4[c], sh_b = sh4[c+64];
  const int m = c & 15, g = c >> 4;   // MFMA lane decomposition

  u32 wr2[32], wz2[32], wn2[32];
  #pragma unroll
  for(int kk = 0; kk < 32; kk++){
    wr2[kk] = whhP[kk*192 + c];
    wz2[kk] = whhP[kk*192 + 64 + c];
    wn2[kk] = whhP[kk*192 + 128 + c];
  }

  hs16[u][c] = 0;
  float hprev = 0.f;

  for(int T = 0; T < 4; T++){
    // ---- stage BN'd x (f16) into swizzled LDS: elem (tp,k) at
    //      [tp][ (((k>>3) ^ (tp&7))<<3) | (k&7) ] ----
    for(int tp = 0; tp < 16; tp++){
      const int p = T*16 + tp;
      const int t = dir ? (NT - 1 - p) : p;
      const size_t xb = ((size_t)s*NT + t)*NH;
      const float xa = b2f(E4[xb + c])*sc_a + sh_a;
      const float xc = b2f(E4[xb + c + 64])*sc_b + sh_b;
      u16* rowp = &xst16[u][tp][0];
      rowp[((((c>>3)    ) ^ (tp&7))<<3) | (c&7)] = f2h(xa);
      rowp[((((c>>3) + 8) ^ (tp&7))<<3) | (c&7)] = f2h(xc);
    }
    // ---- xw = x @ wih^T via MFMA: M=16 steps, N=192, K=128 ----
    f16x8 afr[4];
    #pragma unroll
    for(int ks = 0; ks < 4; ks++){
      const int col8 = (ks*4 + g) ^ (m & 7);
      afr[ks] = *(const f16x8*)&xst16[u][m][col8*8];
    }
    for(int nt = 0; nt < 12; nt++){
      f32x4 acc = {0.f, 0.f, 0.f, 0.f};
      #pragma unroll
      for(int ks = 0; ks < 4; ks++){
        const f16x8 bfr = *(const f16x8*)&wp[(size_t)(nt*16 + m)*NH + ks*32 + g*8];
        acc = __builtin_amdgcn_mfma_f32_16x16x32_f16(afr[ks], bfr, acc, 0, 0, 0);
      }
      #pragma unroll
      for(int r = 0; r < 4; r++)
        xwb16[u][g*4 + r][nt*16 + m] = f2h(acc[r]);
    }
    // ---- recurrent 16 steps (serial) ----
    for(int pp = 0; pp < 16; pp++){
      const float xr = h2f(xwb16[u][pp][c])       + bxr;
      const float xz = h2f(xwb16[u][pp][64 + c])  + bxz;
      const float xn = h2f(xwb16[u][pp][128 + c]) + bxn;
      float hr = bhr, hz = bhz, hn = bhn;
      #pragma unroll
      for(int q = 0; q < 8; q++){
        const uint4 hq = *(const uint4*)&hs16[u][8*q];
        hr = dot2(hq.x, wr2[4*q], hr);   hr = dot2(hq.y, wr2[4*q+1], hr);
        hr = dot2(hq.z, wr2[4*q+2], hr); hr = dot2(hq.w, wr2[4*q+3], hr);
        hz = dot2(hq.x, wz2[4*q], hz);   hz = dot2(hq.y, wz2[4*q+1], hz);
        hz = dot2(hq.z, wz2[4*q+2], hz); hz = dot2(hq.w, wz2[4*q+3], hz);
        hn = dot2(hq.x, wn2[4*q], hn);   hn = dot2(hq.y, wn2[4*q+1], hn);
        hn = dot2(hq.z, wn2[4*q+2], hn); hn = dot2(hq.w, wn2[4*q+3], hn);
      }
      const float rg = 1.f/(1.f + expf(-(xr + hr)));
      const float zg = 1.f/(1.f + expf(-(xz + hz)));
      const float ng = tanhf(xn + rg*hn);
      const float hnew = (1.f - zg)*ng + zg*hprev;
      const u16 hbits = f2h(hnew);
      hs16[u][c] = hbits; hprev = hnew;
      histc[u][pp][c] = hbits;
    }
    // ---- output projections for this chunk's 16 timesteps ----
    // thread (tt = c&15, grp = c>>4): fwd computes prior+encF, rev computes encR
    {
      const int tt = c & 15, grp = c >> 4;
      const int p0 = T*16 + tt;
      const int tg = dir ? (NT - 1 - p0) : p0;
      if(!dir){
        float ap = pb[grp], ae = 0.f;
        for(int kk = 0; kk < 32; kk++){
          u32 hp; __builtin_memcpy(&hp, &histc[u][tt][2*kk], 4);
          const float h0 = h2f((u16)hp), h1 = h2f((u16)(hp >> 16));
          ap += h0*pw[(2*kk)*NNE + grp] + h1*pw[(2*kk+1)*NNE + grp];
          ae += h0*ew[(2*kk)*NNE + grp] + h1*ew[(2*kk+1)*NNE + grp];
        }
        outP[(((size_t)(sb*NT + tg))*NEDGE + se)*NNE + grp] = ap;
        encpF[((size_t)s*NT + tg)*NNE + grp] = __float2bfloat16(ae);
      } else {
        float ae = 0.f;
        for(int kk = 0; kk < 32; kk++){
          u32 hp; __builtin_memcpy(&hp, &histc[u][tt][2*kk], 4);
          const float h0 = h2f((u16)hp), h1 = h2f((u16)(hp >> 16));
          ae += h0*ew[(NR + 2*kk)*NNE + grp] + h1*ew[(NR + 2*kk+1)*NNE + grp];
        }
        encpR[((size_t)s*NT + tg)*NNE + grp] = __float2bfloat16(ae);
      }
    }
  }
  if(!dir) hT[(size_t)s*NR + c] = hprev;
}

// ---------------- merge enc halves + bias ----------------
__global__ void k_add(const bf16* eF, const bf16* eR, const float* eb, float* outE){
  const int i = blockIdx.x*256 + threadIdx.x;
  if(i >= PRIOR_SZ) return;
  const int l = i & 3; const int r2 = i >> 2;
  const int e = r2 % NEDGE; const int r3 = r2 / NEDGE;
  const int t = r3 % NT; const int b = r3 / NT;
  const int s = b*NEDGE + e;
  const size_t src = ((size_t)s*NT + t)*NNE + l;
  outE[i] = b2f(eF[src]) + b2f(eR[src]) + eb[l];
}

extern "C" void kernel_launch(void* const* d_in, const int* in_sizes, int n_in,
                              void* d_out, int out_size, void* d_ws, size_t ws_size,
                              hipStream_t stream)
{
  const size_t NEED = 78888960ull;   // unchanged layout; known ws >= 83,181,568
  if(ws_size < NEED){
    k_fill<<<(out_size + 255)/256, 256, 0, stream>>>((float*)d_out, out_size, 3584.0f);
    return;
  }
  const float* inp  = (const float*)d_in[0];
  const float* m1w1 = (const float*)d_in[1];  const float* m1b1 = (const float*)d_in[2];
  const float* m1w2 = (const float*)d_in[3];  const float* m1b2 = (const float*)d_in[4];
  const float* m1g  = (const float*)d_in[5];  const float* m1be = (const float*)d_in[6];
  const float* m2w1 = (const float*)d_in[7];  const float* m2b1 = (const float*)d_in[8];
  const float* m2w2 = (const float*)d_in[9];  const float* m2b2 = (const float*)d_in[10];
  const float* m2g  = (const float*)d_in[11]; const float* m2be = (const float*)d_in[12];
  const float* m3w1 = (const float*)d_in[13]; const float* m3b1 = (const float*)d_in[14];
  const float* m3w2 = (const float*)d_in[15]; const float* m3b2 = (const float*)d_in[16];
  const float* m3g  = (const float*)d_in[17]; const float* m3be = (const float*)d_in[18];
  const float* m4w1 = (const float*)d_in[19]; const float* m4b1 = (const float*)d_in[20];
  const float* m4w2 = (const float*)d_in[21]; const float* m4b2 = (const float*)d_in[22];
  const float* m4g  = (const float*)d_in[23]; const float* m4be = (const float*)d_in[24];
  const float* wihF = (const float*)d_in[25]; const float* whhF = (const float*)d_in[26];
  const float* bihF = (const float*)d_in[27]; const float* bhhF = (const float*)d_in[28];
  const float* wihR = (const float*)d_in[29]; const float* whhR = (const float*)d_in[30];
  const float* bihR = (const float*)d_in[31]; const float* bhhR = (const float*)d_in[32];
  const float* pw   = (const float*)d_in[33]; const float* pb   = (const float*)d_in[34];
  const float* ew   = (const float*)d_in[35]; const float* eb   = (const float*)d_in[36];

  char* ws = (char*)d_ws;
  float* AUX = (float*)(ws + 0);             // 16 KB reserved
  char*  Xr  = ws + 16384;                   // 6,291,456 B (X1 then X3)
  float* X   = (float*)Xr;
  bf16*  E   = (bf16*)(ws + 16384 + 6291456); // 72,351,744 B (E2 then in-place E4)
  char*  WP  = ws + 78659584;                // 229,376 B MLP weight packs
  u32* w2aP = (u32*)(WP + 0);                // 65,536 B (128 pairs x 128)
  u32* w2bP = (u32*)(WP + 65536);            // 32,768 B (64 pairs x 128)
  u32* w4aP = (u32*)(WP + 98304);            // 98,304 B (192 pairs x 128)
  u32* w4bP = (u32*)(WP + 196608);           // 32,768 B
  // aliases inside X region, valid AFTER mlp4 has consumed X3:
  u16*  wpF   = (u16*)(Xr + 0);              // 49,152 B f16 row-major wih fwd
  u16*  wpR   = (u16*)(Xr + 49152);          // 49,152 B -> 98,304
  u32*  whhPF = (u32*)(Xr + 98304);          // 24,576 B -> 122,880
  u32*  whhPR = (u32*)(Xr + 122880);         // 24,576 B -> 147,456
  bf16* encpF = (bf16*)(Xr + 147456);        // 2,260,992 B -> 2,408,448
  bf16* encpR = (bf16*)(Xr + 2408448);       // 2,260,992 B -> 4,669,440 <= 6,291,456

  float* SUM0 = AUX + 0*128;        float* SUM1 = AUX + 1*128;
  float* SUM2 = AUX + 2*128;        float* SUM3 = AUX + 3*128;
  float* SQ0  = AUX + 512 + 0*128;  float* SQ1  = AUX + 512 + 1*128;
  float* SQ2  = AUX + 512 + 2*128;  float* SQ3  = AUX + 512 + 3*128;
  float* SC0  = AUX + 1024 + 0*128; float* SC1  = AUX + 1024 + 1*128;
  float* SC2  = AUX + 1024 + 2*128; float* SC3  = AUX + 1024 + 3*128;
  float* SH0  = AUX + 1536 + 0*128; float* SH1  = AUX + 1536 + 1*128;
  float* SH2  = AUX + 1536 + 2*128; float* SH3  = AUX + 1536 + 3*128;

  float* outP = (float*)d_out;
  float* outE = outP + PRIOR_SZ;
  float* hT   = outP + 2*PRIOR_SZ;

  k_zero<<<1, 256, 0, stream>>>(AUX);
  k_prep_mlp<<<96, 256, 0, stream>>>(m2w1, m2w2, m4w1, m4w2, w2aP, w2bP, w4aP, w4bP);
  k_mlp1<<<ROWS1/16, 128, 0, stream>>>(inp, m1w1, m1b1, m1w2, m1b2, X, SUM0, SQ0);
  k_bn<<<1, 128, 0, stream>>>(SUM0, SQ0, m1g, m1be, 1.f/ROWS1, SC0, SH0);
  k_mlp_edge<2*NH><<<ROWS2/16, 128, 0, stream>>>(X, SC0, SH0, nullptr, nullptr, nullptr,
                                                 w2aP, m2b1, w2bP, m2b2, E, SUM1, SQ1);
  k_bn<<<1, 128, 0, stream>>>(SUM1, SQ1, m2g, m2be, 1.f/ROWS2, SC1, SH1);
  k_mlp3<<<ROWS1/16, 128, 0, stream>>>(E, SC1, SH1, m3w1, m3b1, m3w2, m3b2, X, SUM2, SQ2);
  k_bn<<<1, 128, 0, stream>>>(SUM2, SQ2, m3g, m3be, 1.f/ROWS1, SC2, SH2);
  k_mlp_edge<3*NH><<<ROWS2/16, 128, 0, stream>>>(X, SC2, SH2, E, SC1, SH1,
                                                 w4aP, m4b1, w4bP, m4b2, E, SUM3, SQ3);
  k_bn<<<1, 128, 0, stream>>>(SUM3, SQ3, m4g, m4be, 1.f/ROWS2, SC3, SH3);
  // X region is now dead -> pack GRU weights into it
  k_prep<<<96, 256, 0, stream>>>(wihF, whhF, wihR, whhR, wpF, whhPF, wpR, whhPR);
  k_gru<<<NSEQ, 128, 0, stream>>>(E, SC3, SH3,
                                  wpF, whhPF, bihF, bhhF,
                                  wpR, whhPR, bihR, bhhR,
                                  pw, pb, ew, encpF, encpR, outP, hT);
  k_add<<<(PRIOR_SZ + 255)/256, 256, 0, stream>>>(encpF, encpR, eb, outE);
}

// Round 2
// 1899.321 us; speedup vs baseline: 1.0147x; 1.0147x over previous
//
#include <hip/hip_runtime.h>
#include <hip/hip_bf16.h>
#include <cstring>

// ---- problem constants ----
#define NB 8
#define NT 64
#define NNODE 24
#define ND 6
#define NH 128
#define NR 64
#define NNE 4
#define NEDGE 552                  // NNODE*(NNODE-1)
#define NSEQ (NB*NEDGE)            // 4416
#define ROWS1 (NB*NNODE*NT)        // 12288
#define ROWS2 (NB*NEDGE*NT)        // 282624
#define PRIOR_SZ (NB*NT*NEDGE*NNE) // 1130496

typedef __hip_bfloat16 bf16;
typedef unsigned short u16;
typedef unsigned int u32;
typedef _Float16 f16;
typedef __attribute__((ext_vector_type(2))) _Float16 f16x2;
typedef __attribute__((ext_vector_type(8))) _Float16 f16x8;
typedef __attribute__((ext_vector_type(4))) float f32x4;

__device__ __forceinline__ float eluf(float x){ return x > 0.f ? x : expm1f(x); }
__device__ __forceinline__ float b2f(bf16 v){ return __bfloat162float(v); }
__device__ __forceinline__ u16 f2h(float x){ f16 h = (f16)x; u16 v; __builtin_memcpy(&v, &h, 2); return v; }
__device__ __forceinline__ float h2f(u16 v){ f16 h; __builtin_memcpy(&h, &v, 2); return (float)h; }
__device__ __forceinline__ u32 packf2(float a, float b){ return (u32)f2h(a) | ((u32)f2h(b) << 16); }

#if defined(__has_builtin)
#if __has_builtin(__builtin_amdgcn_fdot2)
#define HAS_DOT2 1
#endif
#endif

#ifdef HAS_DOT2
__device__ __forceinline__ float dot2(u32 a, u32 b, float c){
  f16x2 av, bv;
  __builtin_memcpy(&av, &a, 4); __builtin_memcpy(&bv, &b, 4);
  return __builtin_amdgcn_fdot2(av, bv, c, false);
}
#else
__device__ __forceinline__ float dot2(u32 a, u32 b, float c){
  return c + h2f((u16)a)*h2f((u16)b) + h2f((u16)(a>>16))*h2f((u16)(b>>16));
}
#endif

// ---------------- diagnostics / setup ----------------
__global__ void k_fill(float* out, int n, float pat){
  const int i = blockIdx.x*256 + threadIdx.x;
  if(i < n) out[i] = pat;
}
__global__ void k_zero(float* aux){
  for(int i = threadIdx.x; i < 1024; i += 256) aux[i] = 0.f;
}

// pack MLP2/MLP4 weights as k-pair f16x2: wP[k2*NH + j] = (w[2k2][j], w[2k2+1][j])
__global__ void k_prep_mlp(const float* w2a, const float* w2b,
                           const float* w4a, const float* w4b,
                           u32* w2aP, u32* w2bP, u32* w4aP, u32* w4bP)
{
  const int i = blockIdx.x*256 + threadIdx.x;
  const int k2 = i >> 7, j = i & 127;
  if(i < 128*128)
    w2aP[k2*NH + j] = packf2(w2a[(2*k2)*NH + j], w2a[(2*k2+1)*NH + j]);
  if(i < 64*128){
    w2bP[k2*NH + j] = packf2(w2b[(2*k2)*NH + j], w2b[(2*k2+1)*NH + j]);
    w4bP[k2*NH + j] = packf2(w4b[(2*k2)*NH + j], w4b[(2*k2+1)*NH + j]);
  }
  if(i < 192*128)
    w4aP[k2*NH + j] = packf2(w4a[(2*k2)*NH + j], w4a[(2*k2+1)*NH + j]);
}

// GRU weight prep (runs after MLP4; X region dead):
//  - wih: straight f16 row-major [192][128]  (MFMA B-operand, B[k][n]=wih[n][k])
//  - whh: pair-transposed f16x2 for the dot2 recurrence (unchanged)
__global__ void k_prep(const float* wihF, const float* whhF,
                       const float* wihR, const float* whhR,
                       u16* wpF, u32* whhPF, u16* wpR, u32* whhPR)
{
  const int i = blockIdx.x*256 + threadIdx.x;
  if(i < 192*128){
    wpF[i] = f2h(wihF[i]);
    wpR[i] = f2h(wihR[i]);
  }
  if(i < 192*32){
    const int r = i >> 5, k2 = i & 31;
    whhPF[k2*192 + r] = packf2(whhF[r*NR + 2*k2], whhF[r*NR + 2*k2 + 1]);
    whhPR[k2*192 + r] = packf2(whhR[r*NR + 2*k2], whhR[r*NR + 2*k2 + 1]);
  }
}

// ---------------- MLP1: (B,N,T,D)->H->H, pre-BN out + channel sums -------------
__global__ __launch_bounds__(128) void k_mlp1(
    const float* inp, const float* w1, const float* b1,
    const float* w2, const float* b2,
    float* X1, float* sum, float* sq)
{
  const int j = threadIdx.x;
  __shared__ float xin[ND];
  __shared__ float h1[NH];
  const float b1j = b1[j], b2j = b2[j];
  float wcol[ND];
  for(int d = 0; d < ND; d++) wcol[d] = w1[d*NH + j];
  float accS = 0.f, accQ = 0.f;
  const int row0 = blockIdx.x*16;
  for(int r = 0; r < 16; r++){
    const int row = row0 + r;
    const int b = row/(NNODE*NT); const int rem = row - b*(NNODE*NT);
    const int n = rem/NT; const int t = rem - n*NT;
    if(j < ND) xin[j] = inp[((b*NT + t)*NNODE + n)*ND + j];
    __syncthreads();
    float a = b1j;
    for(int d = 0; d < ND; d++) a += xin[d]*wcol[d];
    h1[j] = eluf(a);
    __syncthreads();
    float a2 = b2j;
    for(int k = 0; k < NH; k++) a2 += h1[k]*w2[k*NH + j];
    const float h2 = eluf(a2);
    X1[row*NH + j] = h2; accS += h2; accQ += h2*h2;
    __syncthreads();
  }
  atomicAdd(&sum[j], accS); atomicAdd(&sq[j], accQ);
}

// ---------------- BN params ----------------
__global__ void k_bn(const float* sum, const float* sq,
                     const float* g, const float* be,
                     float inv_cnt, float* sc, float* sh)
{
  const int j = threadIdx.x;
  const float m = sum[j]*inv_cnt;
  const float v = fmaxf(sq[j]*inv_cnt - m*m, 0.f);
  const float s = g[j]*rsqrtf(v + 1e-5f);
  sc[j] = s; sh[j] = be[j] - m*s;
}

// ---------------- edge MLPs (MLP2: KIN=256, MLP4: KIN=384), CH=16, f16 dot2 ----
template<int KIN>
__global__ __launch_bounds__(128) void k_mlp_edge(
  const float* Xn, const float* scN, const float* shN,
  const bf16* Ein, const float* scE, const float* shE,
  const u32* w1P, const float* b1, const u32* w2P, const float* b2,
  bf16* Eo, float* sum, float* sq)
{
  const int j = threadIdx.x;
  constexpr int CH = 16;
  __shared__ __align__(16) u16 xin16[CH][KIN];
  __shared__ __align__(16) u16 h1s16[CH][NH];
  const int g0 = blockIdx.x*CH;
  const int b = g0/(NEDGE*NT); const int rem = g0 - b*(NEDGE*NT);
  const int e = rem/NT; const int t0 = rem - e*NT;
  const int snd = e/23, r0 = e - snd*23;
  const int rcv = r0 + (r0 >= snd ? 1 : 0);
  const float sN = scN[j], tN = shN[j];
  float sE = 0.f, tE = 0.f;
  if constexpr(KIN == 3*NH){ sE = scE[j]; tE = shE[j]; }
  const int baseS = ((b*NNODE + snd)*NT + t0)*NH;
  const int baseR = ((b*NNODE + rcv)*NT + t0)*NH;
  for(int r = 0; r < CH; r++){
    xin16[r][j]      = f2h(Xn[baseS + r*NH + j]*sN + tN);
    xin16[r][NH + j] = f2h(Xn[baseR + r*NH + j]*sN + tN);
    if constexpr(KIN == 3*NH)
      xin16[r][2*NH + j] = f2h(b2f(Ein[(size_t)(g0 + r)*NH + j])*sE + tE);
  }
  __syncthreads();
  float acc[CH];
  const float b1j = b1[j];
  #pragma unroll
  for(int r = 0; r < CH; r++) acc[r] = b1j;
  for(int kb = 0; kb < KIN/8; kb++){
    u32 w[4];
    #pragma unroll
    for(int q = 0; q < 4; q++) w[q] = w1P[(size_t)(4*kb + q)*NH + j];
    #pragma unroll
    for(int r = 0; r < CH; r++){
      const uint4 xq = *(const uint4*)&xin16[r][8*kb];
      acc[r] = dot2(xq.x, w[0], acc[r]);
      acc[r] = dot2(xq.y, w[1], acc[r]);
      acc[r] = dot2(xq.z, w[2], acc[r]);
      acc[r] = dot2(xq.w, w[3], acc[r]);
    }
  }
  #pragma unroll
  for(int r = 0; r < CH; r++) h1s16[r][j] = f2h(eluf(acc[r]));
  __syncthreads();
  const float b2j = b2[j];
  #pragma unroll
  for(int r = 0; r < CH; r++) acc[r] = b2j;
  for(int kb = 0; kb < NH/8; kb++){
    u32 w[4];
    #pragma unroll
    for(int q = 0; q < 4; q++) w[q] = w2P[(size_t)(4*kb + q)*NH + j];
    #pragma unroll
    for(int r = 0; r < CH; r++){
      const uint4 hq = *(const uint4*)&h1s16[r][8*kb];
      acc[r] = dot2(hq.x, w[0], acc[r]);
      acc[r] = dot2(hq.y, w[1], acc[r]);
      acc[r] = dot2(hq.z, w[2], acc[r]);
      acc[r] = dot2(hq.w, w[3], acc[r]);
    }
  }
  float accS = 0.f, accQ = 0.f;
  #pragma unroll
  for(int r = 0; r < CH; r++){
    const float h2 = eluf(acc[r]);
    Eo[(size_t)(g0 + r)*NH + j] = __float2bfloat16(h2);
    accS += h2; accQ += h2*h2;
  }
  atomicAdd(&sum[j], accS); atomicAdd(&sq[j], accQ);
}

// ---------------- agg (mean over incoming edges) + MLP3 ----------------
__global__ __launch_bounds__(128) void k_mlp3(
    const bf16* Ein, const float* scE, const float* shE,
    const float* w1, const float* b1, const float* w2, const float* b2,
    float* X3, float* sum, float* sq)
{
  const int j = threadIdx.x;
  __shared__ float xin[NH];
  __shared__ float h1[NH];
  const float sE = scE[j], tE = shE[j];
  float accS = 0.f, accQ = 0.f;
  const int row0 = blockIdx.x*16;
  for(int r = 0; r < 16; r++){
    const int row = row0 + r;
    const int b = row/(NNODE*NT); const int rem = row - b*(NNODE*NT);
    const int n = rem/NT; const int t = rem - n*NT;
    float s = 0.f;
    for(int i = 0; i < NNODE; i++){
      if(i == n) continue;
      const int e = i*23 + (n < i ? n : n - 1);
      s += b2f(Ein[((size_t)(b*NEDGE + e)*NT + t)*NH + j]);
    }
    xin[j] = sE*s*(1.f/23.f) + tE;
    __syncthreads();
    float a = b1[j];
    for(int k = 0; k < NH; k++) a += xin[k]*w1[k*NH + j];
    h1[j] = eluf(a);
    __syncthreads();
    float a2 = b2[j];
    for(int k = 0; k < NH; k++) a2 += h1[k]*w2[k*NH + j];
    const float h2 = eluf(a2);
    X3[row*NH + j] = h2; accS += h2; accQ += h2*h2;
    __syncthreads();
  }
  atomicAdd(&sum[j], accS); atomicAdd(&sq[j], accQ);
}

// ---------------- GRU: 2 independent (seq,dir) units per 128-thread block -----
// Wave-private LDS => NO barriers. Input projection x@wih^T per-16-step chunk
// with v_mfma_f32_16x16x32_f16 (verified round 1: absmax improved).
// __launch_bounds__(128,2): round 1's (128,3) capped the unified reg budget at
// ~170 and the allocator spilled the 96-reg whh arrays to SCRATCH (VGPR=84,
// FETCH 531MB, WRITE 252MB). Budget 256 keeps them resident.
// xwb16 padded to 196/row: stride 392B spreads the 4 g-groups of the MFMA
// result stores across bank offsets {0,8,16,24} -> conflict-free.
__global__ __launch_bounds__(128, 2) void k_gru(
  const bf16* E4, const float* sc4, const float* sh4,
  const u16* wpF, const u32* whhPF, const float* bihF, const float* bhhF,
  const u16* wpR, const u32* whhPR, const float* bihR, const float* bhhR,
  const float* pw, const float* pb, const float* ew,
  bf16* encpF, bf16* encpR, float* outP, float* hT)
{
  __shared__ __align__(16) u16 xst16[2][16][NH];   // 8192 B, 16B-group XOR swizzled
  __shared__ __align__(16) u16 xwb16[2][16][196];  // 12544 B (padded rows)
  __shared__ __align__(16) u16 histc[2][16][66];   // 4224 B (chunk-local history)
  __shared__ __align__(16) u16 hs16[2][NR];        // 256 B
  const int tid = threadIdx.x;
  const int u = tid >> 6, c = tid & 63;
  const int gid = blockIdx.x*2 + u;
  const int dir = (gid >= NSEQ) ? 1 : 0;
  const int s = dir ? (gid - NSEQ) : gid;
  const int sb = s / NEDGE, se = s - sb*NEDGE;
  const u16* wp   = dir ? wpR : wpF;
  const u32* whhP = dir ? whhPR : whhPF;
  const float* bih = dir ? bihR : bihF;
  const float* bhh = dir ? bhhR : bhhF;
  const float bxr = bih[c], bxz = bih[64+c], bxn = bih[128+c];
  const float bhr = bhh[c], bhz = bhh[64+c], bhn = bhh[128+c];
  const float sc_a = sc4[c], sc_b = sc4[c+64];
  const float sh_a = sh4[c], sh_b = sh4[c+64];
  const int m = c & 15, g = c >> 4;   // MFMA lane decomposition

  u32 wr2[32], wz2[32], wn2[32];
  #pragma unroll
  for(int kk = 0; kk < 32; kk++){
    wr2[kk] = whhP[kk*192 + c];
    wz2[kk] = whhP[kk*192 + 64 + c];
    wn2[kk] = whhP[kk*192 + 128 + c];
  }

  hs16[u][c] = 0;
  float hprev = 0.f;

  for(int T = 0; T < 4; T++){
    // ---- stage BN'd x (f16) into swizzled LDS: elem (tp,k) at
    //      [tp][ (((k>>3) ^ (tp&7))<<3) | (k&7) ] ----
    for(int tp = 0; tp < 16; tp++){
      const int p = T*16 + tp;
      const int t = dir ? (NT - 1 - p) : p;
      const size_t xb = ((size_t)s*NT + t)*NH;
      const float xa = b2f(E4[xb + c])*sc_a + sh_a;
      const float xc = b2f(E4[xb + c + 64])*sc_b + sh_b;
      u16* rowp = &xst16[u][tp][0];
      rowp[((((c>>3)    ) ^ (tp&7))<<3) | (c&7)] = f2h(xa);
      rowp[((((c>>3) + 8) ^ (tp&7))<<3) | (c&7)] = f2h(xc);
    }
    // ---- xw = x @ wih^T via MFMA: M=16 steps, N=192, K=128 ----
    f16x8 afr[4];
    #pragma unroll
    for(int ks = 0; ks < 4; ks++){
      const int col8 = (ks*4 + g) ^ (m & 7);
      afr[ks] = *(const f16x8*)&xst16[u][m][col8*8];
    }
    for(int nt = 0; nt < 12; nt++){
      f32x4 acc = {0.f, 0.f, 0.f, 0.f};
      #pragma unroll
      for(int ks = 0; ks < 4; ks++){
        const f16x8 bfr = *(const f16x8*)&wp[(size_t)(nt*16 + m)*NH + ks*32 + g*8];
        acc = __builtin_amdgcn_mfma_f32_16x16x32_f16(afr[ks], bfr, acc, 0, 0, 0);
      }
      #pragma unroll
      for(int r = 0; r < 4; r++)
        xwb16[u][g*4 + r][nt*16 + m] = f2h(acc[r]);
    }
    // ---- recurrent 16 steps (serial) ----
    for(int pp = 0; pp < 16; pp++){
      const float xr = h2f(xwb16[u][pp][c])       + bxr;
      const float xz = h2f(xwb16[u][pp][64 + c])  + bxz;
      const float xn = h2f(xwb16[u][pp][128 + c]) + bxn;
      float hr = bhr, hz = bhz, hn = bhn;
      #pragma unroll
      for(int q = 0; q < 8; q++){
        const uint4 hq = *(const uint4*)&hs16[u][8*q];
        hr = dot2(hq.x, wr2[4*q], hr);   hr = dot2(hq.y, wr2[4*q+1], hr);
        hr = dot2(hq.z, wr2[4*q+2], hr); hr = dot2(hq.w, wr2[4*q+3], hr);
        hz = dot2(hq.x, wz2[4*q], hz);   hz = dot2(hq.y, wz2[4*q+1], hz);
        hz = dot2(hq.z, wz2[4*q+2], hz); hz = dot2(hq.w, wz2[4*q+3], hz);
        hn = dot2(hq.x, wn2[4*q], hn);   hn = dot2(hq.y, wn2[4*q+1], hn);
        hn = dot2(hq.z, wn2[4*q+2], hn); hn = dot2(hq.w, wn2[4*q+3], hn);
      }
      const float rg = 1.f/(1.f + expf(-(xr + hr)));
      const float zg = 1.f/(1.f + expf(-(xz + hz)));
      const float ng = tanhf(xn + rg*hn);
      const float hnew = (1.f - zg)*ng + zg*hprev;
      const u16 hbits = f2h(hnew);
      hs16[u][c] = hbits; hprev = hnew;
      histc[u][pp][c] = hbits;
    }
    // ---- output projections for this chunk's 16 timesteps ----
    // thread (tt = c&15, grp = c>>4): fwd computes prior+encF, rev computes encR
    {
      const int tt = c & 15, grp = c >> 4;
      const int p0 = T*16 + tt;
      const int tg = dir ? (NT - 1 - p0) : p0;
      if(!dir){
        float ap = pb[grp], ae = 0.f;
        for(int kk = 0; kk < 32; kk++){
          u32 hp; __builtin_memcpy(&hp, &histc[u][tt][2*kk], 4);
          const float h0 = h2f((u16)hp), h1 = h2f((u16)(hp >> 16));
          ap += h0*pw[(2*kk)*NNE + grp] + h1*pw[(2*kk+1)*NNE + grp];
          ae += h0*ew[(2*kk)*NNE + grp] + h1*ew[(2*kk+1)*NNE + grp];
        }
        outP[(((size_t)(sb*NT + tg))*NEDGE + se)*NNE + grp] = ap;
        encpF[((size_t)s*NT + tg)*NNE + grp] = __float2bfloat16(ae);
      } else {
        float ae = 0.f;
        for(int kk = 0; kk < 32; kk++){
          u32 hp; __builtin_memcpy(&hp, &histc[u][tt][2*kk], 4);
          const float h0 = h2f((u16)hp), h1 = h2f((u16)(hp >> 16));
          ae += h0*ew[(NR + 2*kk)*NNE + grp] + h1*ew[(NR + 2*kk+1)*NNE + grp];
        }
        encpR[((size_t)s*NT + tg)*NNE + grp] = __float2bfloat16(ae);
      }
    }
  }
  if(!dir) hT[(size_t)s*NR + c] = hprev;
}

// ---------------- merge enc halves + bias ----------------
__global__ void k_add(const bf16* eF, const bf16* eR, const float* eb, float* outE){
  const int i = blockIdx.x*256 + threadIdx.x;
  if(i >= PRIOR_SZ) return;
  const int l = i & 3; const int r2 = i >> 2;
  const int e = r2 % NEDGE; const int r3 = r2 / NEDGE;
  const int t = r3 % NT; const int b = r3 / NT;
  const int s = b*NEDGE + e;
  const size_t src = ((size_t)s*NT + t)*NNE + l;
  outE[i] = b2f(eF[src]) + b2f(eR[src]) + eb[l];
}

extern "C" void kernel_launch(void* const* d_in, const int* in_sizes, int n_in,
                              void* d_out, int out_size, void* d_ws, size_t ws_size,
                              hipStream_t stream)
{
  const size_t NEED = 78888960ull;   // unchanged layout; known ws >= 83,181,568
  if(ws_size < NEED){
    k_fill<<<(out_size + 255)/256, 256, 0, stream>>>((float*)d_out, out_size, 3584.0f);
    return;
  }
  const float* inp  = (const float*)d_in[0];
  const float* m1w1 = (const float*)d_in[1];  const float* m1b1 = (const float*)d_in[2];
  const float* m1w2 = (const float*)d_in[3];  const float* m1b2 = (const float*)d_in[4];
  const float* m1g  = (const float*)d_in[5];  const float* m1be = (const float*)d_in[6];
  const float* m2w1 = (const float*)d_in[7];  const float* m2b1 = (const float*)d_in[8];
  const float* m2w2 = (const float*)d_in[9];  const float* m2b2 = (const float*)d_in[10];
  const float* m2g  = (const float*)d_in[11]; const float* m2be = (const float*)d_in[12];
  const float* m3w1 = (const float*)d_in[13]; const float* m3b1 = (const float*)d_in[14];
  const float* m3w2 = (const float*)d_in[15]; const float* m3b2 = (const float*)d_in[16];
  const float* m3g  = (const float*)d_in[17]; const float* m3be = (const float*)d_in[18];
  const float* m4w1 = (const float*)d_in[19]; const float* m4b1 = (const float*)d_in[20];
  const float* m4w2 = (const float*)d_in[21]; const float* m4b2 = (const float*)d_in[22];
  const float* m4g  = (const float*)d_in[23]; const float* m4be = (const float*)d_in[24];
  const float* wihF = (const float*)d_in[25]; const float* whhF = (const float*)d_in[26];
  const float* bihF = (const float*)d_in[27]; const float* bhhF = (const float*)d_in[28];
  const float* wihR = (const float*)d_in[29]; const float* whhR = (const float*)d_in[30];
  const float* bihR = (const float*)d_in[31]; const float* bhhR = (const float*)d_in[32];
  const float* pw   = (const float*)d_in[33]; const float* pb   = (const float*)d_in[34];
  const float* ew   = (const float*)d_in[35]; const float* eb   = (const float*)d_in[36];

  char* ws = (char*)d_ws;
  float* AUX = (float*)(ws + 0);             // 16 KB reserved
  char*  Xr  = ws + 16384;                   // 6,291,456 B (X1 then X3)
  float* X   = (float*)Xr;
  bf16*  E   = (bf16*)(ws + 16384 + 6291456); // 72,351,744 B (E2 then in-place E4)
  char*  WP  = ws + 78659584;                // 229,376 B MLP weight packs
  u32* w2aP = (u32*)(WP + 0);                // 65,536 B (128 pairs x 128)
  u32* w2bP = (u32*)(WP + 65536);            // 32,768 B (64 pairs x 128)
  u32* w4aP = (u32*)(WP + 98304);            // 98,304 B (192 pairs x 128)
  u32* w4bP = (u32*)(WP + 196608);           // 32,768 B
  // aliases inside X region, valid AFTER mlp4 has consumed X3:
  u16*  wpF   = (u16*)(Xr + 0);              // 49,152 B f16 row-major wih fwd
  u16*  wpR   = (u16*)(Xr + 49152);          // 49,152 B -> 98,304
  u32*  whhPF = (u32*)(Xr + 98304);          // 24,576 B -> 122,880
  u32*  whhPR = (u32*)(Xr + 122880);         // 24,576 B -> 147,456
  bf16* encpF = (bf16*)(Xr + 147456);        // 2,260,992 B -> 2,408,448
  bf16* encpR = (bf16*)(Xr + 2408448);       // 2,260,992 B -> 4,669,440 <= 6,291,456

  float* SUM0 = AUX + 0*128;        float* SUM1 = AUX + 1*128;
  float* SUM2 = AUX + 2*128;        float* SUM3 = AUX + 3*128;
  float* SQ0  = AUX + 512 + 0*128;  float* SQ1  = AUX + 512 + 1*128;
  float* SQ2  = AUX + 512 + 2*128;  float* SQ3  = AUX + 512 + 3*128;
  float* SC0  = AUX + 1024 + 0*128; float* SC1  = AUX + 1024 + 1*128;
  float* SC2  = AUX + 1024 + 2*128; float* SC3  = AUX + 1024 + 3*128;
  float* SH0  = AUX + 1536 + 0*128; float* SH1  = AUX + 1536 + 1*128;
  float* SH2  = AUX + 1536 + 2*128; float* SH3  = AUX + 1536 + 3*128;

  float* outP = (float*)d_out;
  float* outE = outP + PRIOR_SZ;
  float* hT   = outP + 2*PRIOR_SZ;

  k_zero<<<1, 256, 0, stream>>>(AUX);
  k_prep_mlp<<<96, 256, 0, stream>>>(m2w1, m2w2, m4w1, m4w2, w2aP, w2bP, w4aP, w4bP);
  k_mlp1<<<ROWS1/16, 128, 0, stream>>>(inp, m1w1, m1b1, m1w2, m1b2, X, SUM0, SQ0);
  k_bn<<<1, 128, 0, stream>>>(SUM0, SQ0, m1g, m1be, 1.f/ROWS1, SC0, SH0);
  k_mlp_edge<2*NH><<<ROWS2/16, 128, 0, stream>>>(X, SC0, SH0, nullptr, nullptr, nullptr,
                                                 w2aP, m2b1, w2bP, m2b2, E, SUM1, SQ1);
  k_bn<<<1, 128, 0, stream>>>(SUM1, SQ1, m2g, m2be, 1.f/ROWS2, SC1, SH1);
  k_mlp3<<<ROWS1/16, 128, 0, stream>>>(E, SC1, SH1, m3w1, m3b1, m3w2, m3b2, X, SUM2, SQ2);
  k_bn<<<1, 128, 0, stream>>>(SUM2, SQ2, m3g, m3be, 1.f/ROWS1, SC2, SH2);
  k_mlp_edge<3*NH><<<ROWS2/16, 128, 0, stream>>>(X, SC2, SH2, E, SC1, SH1,
                                                 w4aP, m4b1, w4bP, m4b2, E, SUM3, SQ3);
  k_bn<<<1, 128, 0, stream>>>(SUM3, SQ3, m4g, m4be, 1.f/ROWS2, SC3, SH3);
  // X region is now dead -> pack GRU weights into it
  k_prep<<<96, 256, 0, stream>>>(wihF, whhF, wihR, whhR, wpF, whhPF, wpR, whhPR);
  k_gru<<<NSEQ, 128, 0, stream>>>(E, SC3, SH3,
                                  wpF, whhPF, bihF, bhhF,
                                  wpR, whhPR, bihR, bhhR,
                                  pw, pb, ew, encpF, encpR, outP, hT);
  k_add<<<(PRIOR_SZ + 255)/256, 256, 0, stream>>>(encpF, encpR, eb, outE);
}